// Round 22
// baseline (65.830 us; speedup 1.0000x reference)
//
#include <hip/hip_runtime.h>
#include <hip/hip_bf16.h>

typedef __attribute__((ext_vector_type(8))) short bf16x8;
typedef __attribute__((ext_vector_type(4))) float float4_t;
typedef __attribute__((ext_vector_type(2))) float f32x2;
typedef __attribute__((ext_vector_type(16))) float f32x16;
typedef __attribute__((ext_vector_type(4))) int int4v;
typedef __attribute__((ext_vector_type(2))) int int2v;

constexpr int Lseq = 2048;
constexpr int ROWS = 1024;   // H*D floats between consecutive l for fixed (n,h)
constexpr float SCALE_LOG2E = 0.18033688011112042f;  // (1/sqrt(64))*log2(e)

// Fragment-major bf16 sub-images: per (nh, 64-row subtile): 512 frags x 16B = 8 KB.
__device__ short g_Kb[32 * 32 * 4096];   // 8 MB
__device__ short g_Vb[32 * 32 * 4096];   // 8 MB
// kv-split partials: unnormalized O and row-sums per (kvh, nh, qb)
__device__ float g_acc[2][32][16][128][64];   // 16.8 MB
__device__ float g_l[2][32][16][128];         // 0.5 MB

__device__ __forceinline__ int cvtpk(float lo, float hi) {
  int r; asm("v_cvt_pk_bf16_f32 %0, %1, %2" : "=v"(r) : "v"(lo), "v"(hi)); return r;
}
__device__ __forceinline__ f32x2 pkadd(f32x2 a, f32x2 b) {
  f32x2 r; asm("v_pk_add_f32 %0, %1, %2" : "=v"(r) : "v"(a), "v"(b)); return r;
}
__device__ __forceinline__ void plswap(int& a, int& b) {
  int2v r = __builtin_amdgcn_permlane32_swap(a, b, false, false);
  a = r[0]; b = r[1];
}
__device__ __forceinline__ int4v pk8(float4_t a, float4_t b) {
  int4v t;
  t[0] = cvtpk(a[0], a[1]); t[1] = cvtpk(a[2], a[3]);
  t[2] = cvtpk(b[0], b[1]); t[3] = cvtpk(b[2], b[3]);
  return t;
}
__device__ __forceinline__ void dma16(const void* g, void* l) {
  __builtin_amdgcn_global_load_lds(
      (const __attribute__((address_space(1))) void*)g,
      (__attribute__((address_space(3))) void*)l, 16, 0, 0);
}
__device__ __forceinline__ void wait4() {
  asm volatile("s_waitcnt vmcnt(4)" ::: "memory");
  __builtin_amdgcn_sched_barrier(0);
}
__device__ __forceinline__ void wait0() {
  asm volatile("s_waitcnt vmcnt(0)" ::: "memory");
  __builtin_amdgcn_sched_barrier(0);
}

#define MFMA32(A, B, C) __builtin_amdgcn_mfma_f32_32x32x16_bf16((A), (B), (C), 0, 0, 0)

// ---------------- pre-pass (r20, coalesced): f32 K,V -> fragment-major bf16 images ----------------
__global__ __launch_bounds__(256)
void preconv(const float* __restrict__ Kg, const float* __restrict__ Vg) {
  __shared__ float vbuf[64][68];
  const int bid = blockIdx.x;           // 1024 = 32 slices * 32 subtiles
  const int nh = bid >> 5;
  const int kt = bid & 31;
  const size_t base = (size_t)(nh >> 4) * Lseq * ROWS + (size_t)(nh & 15) * 64;
  const int tid = threadIdx.x;
  char* kimg = (char*)g_Kb + ((size_t)nh * 32 + kt) * 8192;
  char* vimg = (char*)g_Vb + ((size_t)nh * 32 + kt) * 8192;

  const int r  = tid >> 2;        // row 0..63
  const int qc = (tid & 3) * 16;  // col chunk base (16 floats)

  {
    const float* src = Kg + base + (size_t)(kt * 64 + r) * ROWS + qc;
    float4_t a = ((const float4_t*)src)[0];
    float4_t b = ((const float4_t*)src)[1];
    float4_t c = ((const float4_t*)src)[2];
    float4_t d = ((const float4_t*)src)[3];
    const int half = r >> 5, lq = r & 31, q = tid & 3;
    *(int4v*)(kimg + (half * 256 + q * 64 + lq) * 16)      = pk8(a, b);
    *(int4v*)(kimg + (half * 256 + q * 64 + 32 + lq) * 16) = pk8(c, d);
  }
  {
    const float* src = Vg + base + (size_t)(kt * 64 + r) * ROWS + qc;
    float4_t a = ((const float4_t*)src)[0];
    float4_t b = ((const float4_t*)src)[1];
    float4_t c = ((const float4_t*)src)[2];
    float4_t d = ((const float4_t*)src)[3];
    *(float4_t*)&vbuf[r][qc]      = a;
    *(float4_t*)&vbuf[r][qc + 4]  = b;
    *(float4_t*)&vbuf[r][qc + 8]  = c;
    *(float4_t*)&vbuf[r][qc + 12] = d;
  }
  __syncthreads();
#pragma unroll
  for (int pp = 0; pp < 2; ++pp) {
    const int f    = tid + pp * 256;
    const int half = f >> 8;
    const int c    = (f >> 6) & 3;
    const int hi   = (f >> 5) & 1;
    const int lq   = f & 31;
    const int col  = half * 32 + lq;
    const int row0 = c * 16 + hi * 8;
    float v[8];
#pragma unroll
    for (int j = 0; j < 8; ++j) v[j] = vbuf[row0 + j][col];
    int4v w;
    w[0] = cvtpk(v[0], v[1]); w[1] = cvtpk(v[2], v[3]);
    w[2] = cvtpk(v[4], v[5]); w[3] = cvtpk(v[6], v[7]);
    *(int4v*)(vimg + f * 16) = w;
  }
}

// ---- attn partial: 1024 blocks x 4 waves = 4096 waves (4/SIMD, 4 blocks/CU @32KB LDS).
//      Block = (nh, qb 128 q-rows, kvh 1024 kv-rows); 16 steps of 64 kv rows.
//      Per step each wave DMAs one contiguous 4KB quarter (w0/w1 K-halves, w2/w3 V).
//      Counted vmcnt(4), raw s_barrier, double-buffered. Writes unnormalized partials. ----
__global__ __launch_bounds__(256, 4)
void attn_part(const float* __restrict__ Qg) {
  __shared__ __align__(16) short kv[2][2][4096];   // [buf][K,V][8KB] = 32 KB

  const int wg  = blockIdx.x;
  const int swz = (wg & 7) * 128 + (wg >> 3);   // XCD-bijective, nwg=1024
  const int nh  = swz >> 5;                     // 0..31
  const int qb  = (swz >> 1) & 15;              // q block 0..15 (128 rows)
  const int kvh = swz & 1;                      // kv half 0..1
  const size_t base = (size_t)(nh >> 4) * Lseq * ROWS + (size_t)(nh & 15) * 64;

  const int tid  = threadIdx.x;
  const int lane = tid & 63;
  const int wid  = tid >> 6;      // wave 0..3: q-panel wid; DMA quarter wid
  const int lq   = lane & 31;
  const int hi   = lane >> 5;

  // ---- Q B-fragments for this wave's 32 rows ----
  bf16x8 qf[4];
  {
    const float* qa = Qg + base + (size_t)(qb * 128 + wid * 32 + lq) * ROWS + hi * 8;
#pragma unroll
    for (int c = 0; c < 4; ++c) {
      float4_t a = *(const float4_t*)(qa + c * 16);
      float4_t b = *(const float4_t*)(qa + c * 16 + 4);
#pragma unroll
      for (int j = 0; j < 4; ++j) { a[j] *= SCALE_LOG2E; b[j] *= SCALE_LOG2E; }
      qf[c] = __builtin_bit_cast(bf16x8, pk8(a, b));
    }
  }
  wait0();   // drain compiler-issued Q loads before the counted-DMA regime

  // wave's DMA source: K image (w0/w1) or V image (w2/w3); 4KB quarter (wid&1)
  const char* gimg = ((wid < 2) ? (const char*)g_Kb : (const char*)g_Vb)
                     + (size_t)nh * 262144 + (size_t)(kvh * 16) * 8192
                     + (size_t)(wid & 1) * 4096 + lane * 16;
  auto stage = [&](int buf, int t) {   // 4 x 1KB DMA chunks of step t's sub-image quarter
    const char* s = gimg + (size_t)t * 8192;
    char* d = (char*)&kv[buf][wid >> 1][0] + (wid & 1) * 4096;
#pragma unroll
    for (int i = 0; i < 4; ++i) dma16(s + i * 1024, d + i * 1024);
  };

  stage(0, 0);
  stage(1, 1);   // queue: 8 outstanding (4 per step)

  float l = 0.f;
  f32x16 acc0 = {}, acc1 = {};
  bf16x8 pa[4];

  auto softmax_pa = [&](f32x16& s0, f32x16& s1) {
#pragma unroll
    for (int r = 0; r < 16; ++r) {
      s0[r] = __builtin_amdgcn_exp2f(s0[r]);
      s1[r] = __builtin_amdgcn_exp2f(s1[r]);
    }
#pragma unroll
    for (int c = 0; c < 4; ++c) {
      const f32x16& sv = (c < 2) ? s0 : s1;
      const int br = (c & 1) * 8;
      int t0 = cvtpk(sv[br + 0], sv[br + 1]);
      int t1 = cvtpk(sv[br + 2], sv[br + 3]);
      int t2 = cvtpk(sv[br + 4], sv[br + 5]);
      int t3 = cvtpk(sv[br + 6], sv[br + 7]);
      plswap(t0, t2);
      plswap(t1, t3);
      int4v tt; tt[0] = t0; tt[1] = t1; tt[2] = t2; tt[3] = t3;
      pa[c] = __builtin_bit_cast(bf16x8, tt);
    }
#define S2(v, i) (f32x2{(v)[2 * (i)], (v)[2 * (i) + 1]})
    f32x2 u0 = pkadd(S2(s0, 0), S2(s0, 1));
    f32x2 u1 = pkadd(S2(s0, 2), S2(s0, 3));
    f32x2 u2 = pkadd(S2(s0, 4), S2(s0, 5));
    f32x2 u3 = pkadd(S2(s0, 6), S2(s0, 7));
    f32x2 u4 = pkadd(S2(s1, 0), S2(s1, 1));
    f32x2 u5 = pkadd(S2(s1, 2), S2(s1, 3));
    f32x2 u6 = pkadd(S2(s1, 4), S2(s1, 5));
    f32x2 u7 = pkadd(S2(s1, 6), S2(s1, 7));
    u0 = pkadd(u0, u1); u2 = pkadd(u2, u3);
    u4 = pkadd(u4, u5); u6 = pkadd(u6, u7);
    u0 = pkadd(u0, u2); u4 = pkadd(u4, u6);
    u0 = pkadd(u0, u4);
    l += u0[0] + u0[1];
#undef S2
  };

#pragma unroll 1
  for (int t = 0; t < 16; ++t) {
    wait4();                                // my quarter of step t landed (t+1 in flight)
    __builtin_amdgcn_s_barrier();           // all 4 quarters of step t in LDS
    __builtin_amdgcn_sched_barrier(0);

    const int buf = t & 1;
    const char* kld = (const char*)&kv[buf][0][0] + lane * 16;
    const char* vld = (const char*)&kv[buf][1][0] + lane * 16;

    f32x16 s0 = {}, s1 = {};
#pragma unroll
    for (int c = 0; c < 4; ++c) {
      s0 = MFMA32(*(const bf16x8*)(kld + c * 1024),        qf[c], s0);
      s1 = MFMA32(*(const bf16x8*)(kld + 4096 + c * 1024), qf[c], s1);
    }
    softmax_pa(s0, s1);
#pragma unroll
    for (int c = 0; c < 4; ++c) {
      acc0 = MFMA32(pa[c], *(const bf16x8*)(vld + c * 1024),        acc0);
      acc1 = MFMA32(pa[c], *(const bf16x8*)(vld + 4096 + c * 1024), acc1);
    }

    __builtin_amdgcn_sched_barrier(0);
    __builtin_amdgcn_s_barrier();           // all reads of buf done block-wide
    stage(buf, (t + 2) & 15);               // DMA step t+2 (wrap = harmless dummy)
  }
  wait0();   // drain the dummy wrap DMAs

  // ---- merge cross-half l; write unnormalized partials ----
  {
    int a = __float_as_int(l), b = a;
    plswap(a, b);
    l = __int_as_float(a) + __int_as_float(b);
  }
  if (hi == 0) g_l[kvh][nh][qb][wid * 32 + lq] = l;
#pragma unroll
  for (int r = 0; r < 16; ++r) {
    int qr = (r & 3) + 8 * (r >> 2) + 4 * hi;
    g_acc[kvh][nh][qb][wid * 32 + qr][lq]      = acc0[r];
    g_acc[kvh][nh][qb][wid * 32 + qr][32 + lq] = acc1[r];
  }
}

// ---- merge: O = (acc0 + acc1) / (l0 + l1), coalesced ----
__global__ __launch_bounds__(256)
void merge(float* __restrict__ Og) {
  const int flat = blockIdx.x * 256 + threadIdx.x;   // 0..524287, 8 floats each
  const int c8  = (flat & 7) * 8;
  const int row = (flat >> 3) & 127;
  const int qb  = (flat >> 10) & 15;
  const int nh  = flat >> 14;
  const float* a0 = &g_acc[0][nh][qb][row][c8];
  const float* a1 = &g_acc[1][nh][qb][row][c8];
  const float inv = 1.0f / (g_l[0][nh][qb][row] + g_l[1][nh][qb][row]);
  const size_t base = (size_t)(nh >> 4) * Lseq * ROWS + (size_t)(nh & 15) * 64;
  float* o = Og + base + (size_t)(qb * 128 + row) * ROWS + c8;
  float4_t x0 = *(const float4_t*)a0 + *(const float4_t*)a1;
  float4_t x1 = *(const float4_t*)(a0 + 4) + *(const float4_t*)(a1 + 4);
#pragma unroll
  for (int j = 0; j < 4; ++j) { x0[j] *= inv; x1[j] *= inv; }
  *(float4_t*)o       = x0;
  *(float4_t*)(o + 4) = x1;
}

extern "C" void kernel_launch(void* const* d_in, const int* in_sizes, int n_in,
                              void* d_out, int out_size, void* d_ws, size_t ws_size,
                              hipStream_t stream) {
  const float* Q = (const float*)d_in[0];
  const float* K = (const float*)d_in[1];
  const float* V = (const float*)d_in[2];
  float* O = (float*)d_out;
  preconv<<<dim3(1024), dim3(256), 0, stream>>>(K, V);
  attn_part<<<dim3(1024), dim3(256), 0, stream>>>(Q);
  merge<<<dim3(2048), dim3(256), 0, stream>>>(O);
}

// Round 23
// 64.468 us; speedup vs baseline: 1.0211x; 1.0211x over previous
//
#include <hip/hip_runtime.h>
#include <hip/hip_bf16.h>

typedef __attribute__((ext_vector_type(8))) short bf16x8;
typedef __attribute__((ext_vector_type(4))) float float4_t;
typedef __attribute__((ext_vector_type(2))) float f32x2;
typedef __attribute__((ext_vector_type(16))) float f32x16;
typedef __attribute__((ext_vector_type(4))) int int4v;
typedef __attribute__((ext_vector_type(2))) int int2v;

constexpr int Lseq = 2048;
constexpr int ROWS = 1024;   // H*D floats between consecutive l for fixed (n,h)
constexpr float SCALE_LOG2E = 0.18033688011112042f;  // (1/sqrt(64))*log2(e)

// Fragment-major bf16 sub-images: per (nh, 64-row subtile): 512 frags x 16B = 8 KB.
__device__ short g_Kb[32 * 32 * 4096];   // 8 MB
__device__ short g_Vb[32 * 32 * 4096];   // 8 MB
// kv-split partials: unnormalized O and row-sums per (kvh, nh, qb)
__device__ float g_acc[2][32][16][128][64];   // 16.8 MB
__device__ float g_l[2][32][16][128];         // 0.5 MB

__device__ __forceinline__ int cvtpk(float lo, float hi) {
  int r; asm("v_cvt_pk_bf16_f32 %0, %1, %2" : "=v"(r) : "v"(lo), "v"(hi)); return r;
}
__device__ __forceinline__ f32x2 pkadd(f32x2 a, f32x2 b) {
  f32x2 r; asm("v_pk_add_f32 %0, %1, %2" : "=v"(r) : "v"(a), "v"(b)); return r;
}
__device__ __forceinline__ void plswap(int& a, int& b) {
  int2v r = __builtin_amdgcn_permlane32_swap(a, b, false, false);
  a = r[0]; b = r[1];
}
__device__ __forceinline__ int4v pk8(float4_t a, float4_t b) {
  int4v t;
  t[0] = cvtpk(a[0], a[1]); t[1] = cvtpk(a[2], a[3]);
  t[2] = cvtpk(b[0], b[1]); t[3] = cvtpk(b[2], b[3]);
  return t;
}
__device__ __forceinline__ void dma16(const void* g, void* l) {
  __builtin_amdgcn_global_load_lds(
      (const __attribute__((address_space(1))) void*)g,
      (__attribute__((address_space(3))) void*)l, 16, 0, 0);
}
__device__ __forceinline__ void wait8() {
  asm volatile("s_waitcnt vmcnt(8)" ::: "memory");
  __builtin_amdgcn_sched_barrier(0);
}
__device__ __forceinline__ void wait0() {
  asm volatile("s_waitcnt vmcnt(0)" ::: "memory");
  __builtin_amdgcn_sched_barrier(0);
}

#define MFMA32(A, B, C) __builtin_amdgcn_mfma_f32_32x32x16_bf16((A), (B), (C), 0, 0, 0)

// ---------------- pre-pass (r20, coalesced): f32 K,V -> fragment-major bf16 images ----------------
__global__ __launch_bounds__(256)
void preconv(const float* __restrict__ Kg, const float* __restrict__ Vg) {
  __shared__ float vbuf[64][68];
  const int bid = blockIdx.x;           // 1024 = 32 slices * 32 subtiles
  const int nh = bid >> 5;
  const int kt = bid & 31;
  const size_t base = (size_t)(nh >> 4) * Lseq * ROWS + (size_t)(nh & 15) * 64;
  const int tid = threadIdx.x;
  char* kimg = (char*)g_Kb + ((size_t)nh * 32 + kt) * 8192;
  char* vimg = (char*)g_Vb + ((size_t)nh * 32 + kt) * 8192;

  const int r  = tid >> 2;        // row 0..63
  const int qc = (tid & 3) * 16;  // col chunk base (16 floats)

  {
    const float* src = Kg + base + (size_t)(kt * 64 + r) * ROWS + qc;
    float4_t a = ((const float4_t*)src)[0];
    float4_t b = ((const float4_t*)src)[1];
    float4_t c = ((const float4_t*)src)[2];
    float4_t d = ((const float4_t*)src)[3];
    const int half = r >> 5, lq = r & 31, q = tid & 3;
    *(int4v*)(kimg + (half * 256 + q * 64 + lq) * 16)      = pk8(a, b);
    *(int4v*)(kimg + (half * 256 + q * 64 + 32 + lq) * 16) = pk8(c, d);
  }
  {
    const float* src = Vg + base + (size_t)(kt * 64 + r) * ROWS + qc;
    float4_t a = ((const float4_t*)src)[0];
    float4_t b = ((const float4_t*)src)[1];
    float4_t c = ((const float4_t*)src)[2];
    float4_t d = ((const float4_t*)src)[3];
    *(float4_t*)&vbuf[r][qc]      = a;
    *(float4_t*)&vbuf[r][qc + 4]  = b;
    *(float4_t*)&vbuf[r][qc + 8]  = c;
    *(float4_t*)&vbuf[r][qc + 12] = d;
  }
  __syncthreads();
#pragma unroll
  for (int pp = 0; pp < 2; ++pp) {
    const int f    = tid + pp * 256;
    const int half = f >> 8;
    const int c    = (f >> 6) & 3;
    const int hi   = (f >> 5) & 1;
    const int lq   = f & 31;
    const int col  = half * 32 + lq;
    const int row0 = c * 16 + hi * 8;
    float v[8];
#pragma unroll
    for (int j = 0; j < 8; ++j) v[j] = vbuf[row0 + j][col];
    int4v w;
    w[0] = cvtpk(v[0], v[1]); w[1] = cvtpk(v[2], v[3]);
    w[2] = cvtpk(v[4], v[5]); w[3] = cvtpk(v[6], v[7]);
    *(int4v*)(vimg + f * 16) = w;
  }
}

// ---- attn partial: 1024 blocks x 4 waves; 3-DEEP circular staging (48KB LDS ->
//      3 blocks/CU, launch_bounds(256,3)). Block = (nh, qb 128 q-rows, kvh 1024 kv);
//      16 steps of 64 kv rows; per step each wave DMAs one contiguous 4KB quarter.
//      Queue: 12 outstanding (3 steps x 4); wait vmcnt(8) -> current step landed,
//      2 steps still in flight. Raw s_barrier. Writes unnormalized partials. ----
__global__ __launch_bounds__(256, 3)
void attn_part(const float* __restrict__ Qg) {
  __shared__ __align__(16) short kv[3][2][4096];   // [buf][K,V][8KB] = 48 KB

  const int wg  = blockIdx.x;
  const int swz = (wg & 7) * 128 + (wg >> 3);   // XCD-bijective, nwg=1024
  const int nh  = swz >> 5;                     // 0..31
  const int qb  = (swz >> 1) & 15;              // q block 0..15 (128 rows)
  const int kvh = swz & 1;                      // kv half 0..1
  const size_t base = (size_t)(nh >> 4) * Lseq * ROWS + (size_t)(nh & 15) * 64;

  const int tid  = threadIdx.x;
  const int lane = tid & 63;
  const int wid  = tid >> 6;      // wave 0..3: q-panel wid; DMA quarter wid
  const int lq   = lane & 31;
  const int hi   = lane >> 5;

  // ---- Q B-fragments for this wave's 32 rows ----
  bf16x8 qf[4];
  {
    const float* qa = Qg + base + (size_t)(qb * 128 + wid * 32 + lq) * ROWS + hi * 8;
#pragma unroll
    for (int c = 0; c < 4; ++c) {
      float4_t a = *(const float4_t*)(qa + c * 16);
      float4_t b = *(const float4_t*)(qa + c * 16 + 4);
#pragma unroll
      for (int j = 0; j < 4; ++j) { a[j] *= SCALE_LOG2E; b[j] *= SCALE_LOG2E; }
      qf[c] = __builtin_bit_cast(bf16x8, pk8(a, b));
    }
  }
  wait0();   // drain compiler-issued Q loads before the counted-DMA regime

  // wave's DMA source: K image (w0/w1) or V image (w2/w3); 4KB quarter (wid&1)
  const char* gimg = ((wid < 2) ? (const char*)g_Kb : (const char*)g_Vb)
                     + (size_t)nh * 262144 + (size_t)(kvh * 16) * 8192
                     + (size_t)(wid & 1) * 4096 + lane * 16;
  auto stage = [&](int buf, int t) {   // 4 x 1KB DMA chunks of step t's sub-image quarter
    const char* s = gimg + (size_t)t * 8192;
    char* d = (char*)&kv[buf][wid >> 1][0] + (wid & 1) * 4096;
#pragma unroll
    for (int i = 0; i < 4; ++i) dma16(s + i * 1024, d + i * 1024);
  };

  stage(0, 0);
  stage(1, 1);
  stage(2, 2);   // queue: 12 outstanding (4 per step, 3 steps deep)

  float l = 0.f;
  f32x16 acc0 = {}, acc1 = {};
  bf16x8 pa[4];

  auto softmax_pa = [&](f32x16& s0, f32x16& s1) {
#pragma unroll
    for (int r = 0; r < 16; ++r) {
      s0[r] = __builtin_amdgcn_exp2f(s0[r]);
      s1[r] = __builtin_amdgcn_exp2f(s1[r]);
    }
#pragma unroll
    for (int c = 0; c < 4; ++c) {
      const f32x16& sv = (c < 2) ? s0 : s1;
      const int br = (c & 1) * 8;
      int t0 = cvtpk(sv[br + 0], sv[br + 1]);
      int t1 = cvtpk(sv[br + 2], sv[br + 3]);
      int t2 = cvtpk(sv[br + 4], sv[br + 5]);
      int t3 = cvtpk(sv[br + 6], sv[br + 7]);
      plswap(t0, t2);
      plswap(t1, t3);
      int4v tt; tt[0] = t0; tt[1] = t1; tt[2] = t2; tt[3] = t3;
      pa[c] = __builtin_bit_cast(bf16x8, tt);
    }
#define S2(v, i) (f32x2{(v)[2 * (i)], (v)[2 * (i) + 1]})
    f32x2 u0 = pkadd(S2(s0, 0), S2(s0, 1));
    f32x2 u1 = pkadd(S2(s0, 2), S2(s0, 3));
    f32x2 u2 = pkadd(S2(s0, 4), S2(s0, 5));
    f32x2 u3 = pkadd(S2(s0, 6), S2(s0, 7));
    f32x2 u4 = pkadd(S2(s1, 0), S2(s1, 1));
    f32x2 u5 = pkadd(S2(s1, 2), S2(s1, 3));
    f32x2 u6 = pkadd(S2(s1, 4), S2(s1, 5));
    f32x2 u7 = pkadd(S2(s1, 6), S2(s1, 7));
    u0 = pkadd(u0, u1); u2 = pkadd(u2, u3);
    u4 = pkadd(u4, u5); u6 = pkadd(u6, u7);
    u0 = pkadd(u0, u2); u4 = pkadd(u4, u6);
    u0 = pkadd(u0, u4);
    l += u0[0] + u0[1];
#undef S2
  };

  int buf = 0;
#pragma unroll 1
  for (int t = 0; t < 16; ++t) {
    wait8();                                // 12 outstanding -> oldest 4 (step t) landed
    __builtin_amdgcn_s_barrier();           // all 4 quarters of step t in LDS
    __builtin_amdgcn_sched_barrier(0);

    const char* kld = (const char*)&kv[buf][0][0] + lane * 16;
    const char* vld = (const char*)&kv[buf][1][0] + lane * 16;

    f32x16 s0 = {}, s1 = {};
#pragma unroll
    for (int c = 0; c < 4; ++c) {
      s0 = MFMA32(*(const bf16x8*)(kld + c * 1024),        qf[c], s0);
      s1 = MFMA32(*(const bf16x8*)(kld + 4096 + c * 1024), qf[c], s1);
    }
    softmax_pa(s0, s1);
#pragma unroll
    for (int c = 0; c < 4; ++c) {
      acc0 = MFMA32(pa[c], *(const bf16x8*)(vld + c * 1024),        acc0);
      acc1 = MFMA32(pa[c], *(const bf16x8*)(vld + 4096 + c * 1024), acc1);
    }

    __builtin_amdgcn_sched_barrier(0);
    __builtin_amdgcn_s_barrier();           // all reads of buf done block-wide
    stage(buf, (t + 3) & 15);               // DMA step t+3 into just-freed buf (tail: dummy)
    buf = (buf == 2) ? 0 : buf + 1;
  }
  wait0();   // drain the dummy wrap DMAs

  // ---- merge cross-half l; write unnormalized partials ----
  {
    int a = __float_as_int(l), b = a;
    plswap(a, b);
    l = __int_as_float(a) + __int_as_float(b);
  }
  if (hi == 0) g_l[kvh][nh][qb][wid * 32 + lq] = l;
#pragma unroll
  for (int r = 0; r < 16; ++r) {
    int qr = (r & 3) + 8 * (r >> 2) + 4 * hi;
    g_acc[kvh][nh][qb][wid * 32 + qr][lq]      = acc0[r];
    g_acc[kvh][nh][qb][wid * 32 + qr][32 + lq] = acc1[r];
  }
}

// ---- merge: O = (acc0 + acc1) / (l0 + l1), coalesced ----
__global__ __launch_bounds__(256)
void merge(float* __restrict__ Og) {
  const int flat = blockIdx.x * 256 + threadIdx.x;   // 0..524287, 8 floats each
  const int c8  = (flat & 7) * 8;
  const int row = (flat >> 3) & 127;
  const int qb  = (flat >> 10) & 15;
  const int nh  = flat >> 14;
  const float* a0 = &g_acc[0][nh][qb][row][c8];
  const float* a1 = &g_acc[1][nh][qb][row][c8];
  const float inv = 1.0f / (g_l[0][nh][qb][row] + g_l[1][nh][qb][row]);
  const size_t base = (size_t)(nh >> 4) * Lseq * ROWS + (size_t)(nh & 15) * 64;
  float* o = Og + base + (size_t)(qb * 128 + row) * ROWS + c8;
  float4_t x0 = *(const float4_t*)a0 + *(const float4_t*)a1;
  float4_t x1 = *(const float4_t*)(a0 + 4) + *(const float4_t*)(a1 + 4);
#pragma unroll
  for (int j = 0; j < 4; ++j) { x0[j] *= inv; x1[j] *= inv; }
  *(float4_t*)o       = x0;
  *(float4_t*)(o + 4) = x1;
}

extern "C" void kernel_launch(void* const* d_in, const int* in_sizes, int n_in,
                              void* d_out, int out_size, void* d_ws, size_t ws_size,
                              hipStream_t stream) {
  const float* Q = (const float*)d_in[0];
  const float* K = (const float*)d_in[1];
  const float* V = (const float*)d_in[2];
  float* O = (float*)d_out;
  preconv<<<dim3(1024), dim3(256), 0, stream>>>(K, V);
  attn_part<<<dim3(1024), dim3(256), 0, stream>>>(Q);
  merge<<<dim3(2048), dim3(256), 0, stream>>>(O);
}

// Round 24
// 56.427 us; speedup vs baseline: 1.1666x; 1.1425x over previous
//
#include <hip/hip_runtime.h>
#include <hip/hip_bf16.h>

typedef __attribute__((ext_vector_type(8))) short bf16x8;
typedef __attribute__((ext_vector_type(4))) float float4_t;
typedef __attribute__((ext_vector_type(2))) float f32x2;
typedef __attribute__((ext_vector_type(16))) float f32x16;
typedef __attribute__((ext_vector_type(4))) int int4v;
typedef __attribute__((ext_vector_type(2))) int int2v;

constexpr int Lseq = 2048;
constexpr int ROWS = 1024;   // H*D floats between consecutive l for fixed (n,h)
constexpr float SCALE_LOG2E = 0.18033688011112042f;  // (1/sqrt(64))*log2(e)

// Fragment-major bf16 sub-images: per (nh, 64-row subtile): 512 frags x 16B = 8 KB.
// frag f = half*256 + c*64 + hi*32 + lq; K elem = K[sub*64+half*32+lq][c*16+hi*8+j],
// V elem = V^T (rows=d, cols=kv within subtile).
__device__ short g_Kb[32 * 32 * 4096];   // 8 MB
__device__ short g_Vb[32 * 32 * 4096];   // 8 MB

__device__ __forceinline__ int cvtpk(float lo, float hi) {
  int r; asm("v_cvt_pk_bf16_f32 %0, %1, %2" : "=v"(r) : "v"(lo), "v"(hi)); return r;
}
__device__ __forceinline__ f32x2 pkadd(f32x2 a, f32x2 b) {
  f32x2 r; asm("v_pk_add_f32 %0, %1, %2" : "=v"(r) : "v"(a), "v"(b)); return r;
}
__device__ __forceinline__ void plswap(int& a, int& b) {
  int2v r = __builtin_amdgcn_permlane32_swap(a, b, false, false);
  a = r[0]; b = r[1];
}
__device__ __forceinline__ int4v pk8(float4_t a, float4_t b) {
  int4v t;
  t[0] = cvtpk(a[0], a[1]); t[1] = cvtpk(a[2], a[3]);
  t[2] = cvtpk(b[0], b[1]); t[3] = cvtpk(b[2], b[3]);
  return t;
}
__device__ __forceinline__ void dma16(const void* g, void* l) {
  __builtin_amdgcn_global_load_lds(
      (const __attribute__((address_space(1))) void*)g,
      (__attribute__((address_space(3))) void*)l, 16, 0, 0);
}
__device__ __forceinline__ void wait8() {
  asm volatile("s_waitcnt vmcnt(8)" ::: "memory");
  __builtin_amdgcn_sched_barrier(0);
}
__device__ __forceinline__ void wait0() {
  asm volatile("s_waitcnt vmcnt(0)" ::: "memory");
  __builtin_amdgcn_sched_barrier(0);
}

#define MFMA32(A, B, C) __builtin_amdgcn_mfma_f32_32x32x16_bf16((A), (B), (C), 0, 0, 0)

// ---------------- pre-pass (coalesced): f32 K,V -> fragment-major bf16 images ----------------
__global__ __launch_bounds__(256)
void preconv(const float* __restrict__ Kg, const float* __restrict__ Vg) {
  __shared__ float vbuf[64][68];        // padded rows; 16B-aligned row base
  const int bid = blockIdx.x;           // 1024 = 32 slices * 32 subtiles
  const int nh = bid >> 5;
  const int kt = bid & 31;
  const size_t base = (size_t)(nh >> 4) * Lseq * ROWS + (size_t)(nh & 15) * 64;
  const int tid = threadIdx.x;
  char* kimg = (char*)g_Kb + ((size_t)nh * 32 + kt) * 8192;
  char* vimg = (char*)g_Vb + ((size_t)nh * 32 + kt) * 8192;

  const int r  = tid >> 2;        // row 0..63
  const int qc = (tid & 3) * 16;  // col chunk base (16 floats)

  // ---- K: coalesced row read (4 thr x 64B per row) -> 2 frags each ----
  {
    const float* src = Kg + base + (size_t)(kt * 64 + r) * ROWS + qc;
    float4_t a = ((const float4_t*)src)[0];
    float4_t b = ((const float4_t*)src)[1];
    float4_t c = ((const float4_t*)src)[2];
    float4_t d = ((const float4_t*)src)[3];
    const int half = r >> 5, lq = r & 31, q = tid & 3;
    *(int4v*)(kimg + (half * 256 + q * 64 + lq) * 16)      = pk8(a, b);  // hi=0
    *(int4v*)(kimg + (half * 256 + q * 64 + 32 + lq) * 16) = pk8(c, d);  // hi=1
  }
  // ---- V: coalesced row read into LDS ----
  {
    const float* src = Vg + base + (size_t)(kt * 64 + r) * ROWS + qc;
    float4_t a = ((const float4_t*)src)[0];
    float4_t b = ((const float4_t*)src)[1];
    float4_t c = ((const float4_t*)src)[2];
    float4_t d = ((const float4_t*)src)[3];
    *(float4_t*)&vbuf[r][qc]      = a;
    *(float4_t*)&vbuf[r][qc + 4]  = b;
    *(float4_t*)&vbuf[r][qc + 8]  = c;
    *(float4_t*)&vbuf[r][qc + 12] = d;
  }
  __syncthreads();
  // ---- V^T frags from LDS columns (stride 68: conflict-spread) ----
#pragma unroll
  for (int pp = 0; pp < 2; ++pp) {
    const int f    = tid + pp * 256;     // fragment id 0..511
    const int half = f >> 8;
    const int c    = (f >> 6) & 3;
    const int hi   = (f >> 5) & 1;
    const int lq   = f & 31;
    const int col  = half * 32 + lq;
    const int row0 = c * 16 + hi * 8;
    float v[8];
#pragma unroll
    for (int j = 0; j < 8; ++j) v[j] = vbuf[row0 + j][col];
    int4v w;
    w[0] = cvtpk(v[0], v[1]); w[1] = cvtpk(v[2], v[3]);
    w[2] = cvtpk(v[4], v[5]); w[3] = cvtpk(v[6], v[7]);
    *(int4v*)(vimg + f * 16) = w;
  }
}

// ---- main (best measured, r16/r21): 512 blocks x 4 waves; 128 q-rows/block (one
//      32-row panel per wave). K-step = 128 rows; per step each wave DMAs one 8KB
//      chunk (w0/w1 K, w2/w3 V). Double-buffered 64KB LDS, counted vmcnt(8), raw
//      s_barrier. pkadd row-sum. NO sched_group_barrier (r11/r17: SGB-induced spills
//      corrupt the counted-vmcnt FIFO). Uniform dummy wrap DMAs keep vmcnt counts valid. ----
__global__ __launch_bounds__(256, 2)
void attn_fwd(const float* __restrict__ Qg, float* __restrict__ Og) {
  __shared__ __align__(16) short kv[2][4][4096];   // [buf][Klo,Khi,Vlo,Vhi][8KB] = 64 KB

  const int wg  = blockIdx.x;
  const int swz = (wg & 7) * 64 + (wg >> 3);    // XCD-bijective, nwg=512
  const int nh  = swz >> 4;                     // 0..31
  const int qb  = swz & 15;                     // q block 0..15 (128 rows)
  const size_t base = (size_t)(nh >> 4) * Lseq * ROWS + (size_t)(nh & 15) * 64;

  const int tid  = threadIdx.x;
  const int lane = tid & 63;
  const int wid  = tid >> 6;      // wave 0..3: q-panel wid; DMA chunk wid
  const int lq   = lane & 31;
  const int hi   = lane >> 5;

  // ---- Q B-fragments for this wave's 32 rows ----
  bf16x8 qf[4];
  {
    const float* qa = Qg + base + (size_t)(qb * 128 + wid * 32 + lq) * ROWS + hi * 8;
#pragma unroll
    for (int c = 0; c < 4; ++c) {
      float4_t a = *(const float4_t*)(qa + c * 16);
      float4_t b = *(const float4_t*)(qa + c * 16 + 4);
#pragma unroll
      for (int j = 0; j < 4; ++j) { a[j] *= SCALE_LOG2E; b[j] *= SCALE_LOG2E; }
      qf[c] = __builtin_bit_cast(bf16x8, pk8(a, b));
    }
  }
  wait0();   // drain compiler-issued Q loads before the counted-DMA regime

  // wave's DMA source: K image for wid 0/1, V image for wid 2/3 (lo/hi 64-row half)
  const char* gimg = ((wid < 2) ? (const char*)g_Kb : (const char*)g_Vb)
                     + (size_t)nh * 262144 + (size_t)(wid & 1) * 8192 + lane * 16;
  auto stage = [&](int buf, int t) {   // 8 x 1KB DMA chunks of step t's sub-image
    const char* s = gimg + (size_t)t * 16384;
    char* d = (char*)&kv[buf][wid][0];
#pragma unroll
    for (int i = 0; i < 8; ++i) dma16(s + i * 1024, d + i * 1024);
  };

  stage(0, 0);
  stage(1, 1);   // queue: 16 outstanding (8 per step)

  float l = 0.f;
  f32x16 acc0 = {}, acc1 = {};
  bf16x8 pa[4];

  auto softmax_pa = [&](f32x16& s0, f32x16& s1) {
#pragma unroll
    for (int r = 0; r < 16; ++r) {
      s0[r] = __builtin_amdgcn_exp2f(s0[r]);
      s1[r] = __builtin_amdgcn_exp2f(s1[r]);
    }
#pragma unroll
    for (int c = 0; c < 4; ++c) {
      const f32x16& sv = (c < 2) ? s0 : s1;
      const int br = (c & 1) * 8;
      int t0 = cvtpk(sv[br + 0], sv[br + 1]);
      int t1 = cvtpk(sv[br + 2], sv[br + 3]);
      int t2 = cvtpk(sv[br + 4], sv[br + 5]);
      int t3 = cvtpk(sv[br + 6], sv[br + 7]);
      plswap(t0, t2);
      plswap(t1, t3);
      int4v tt; tt[0] = t0; tt[1] = t1; tt[2] = t2; tt[3] = t3;
      pa[c] = __builtin_bit_cast(bf16x8, tt);
    }
#define S2(v, i) (f32x2{(v)[2 * (i)], (v)[2 * (i) + 1]})
    f32x2 u0 = pkadd(S2(s0, 0), S2(s0, 1));
    f32x2 u1 = pkadd(S2(s0, 2), S2(s0, 3));
    f32x2 u2 = pkadd(S2(s0, 4), S2(s0, 5));
    f32x2 u3 = pkadd(S2(s0, 6), S2(s0, 7));
    f32x2 u4 = pkadd(S2(s1, 0), S2(s1, 1));
    f32x2 u5 = pkadd(S2(s1, 2), S2(s1, 3));
    f32x2 u6 = pkadd(S2(s1, 4), S2(s1, 5));
    f32x2 u7 = pkadd(S2(s1, 6), S2(s1, 7));
    u0 = pkadd(u0, u1); u2 = pkadd(u2, u3);
    u4 = pkadd(u4, u5); u6 = pkadd(u6, u7);
    u0 = pkadd(u0, u2); u4 = pkadd(u4, u6);
    u0 = pkadd(u0, u4);
    l += u0[0] + u0[1];
#undef S2
  };

#pragma unroll 1
  for (int t = 0; t < 16; ++t) {
    wait8();                                // my chunk of step t landed (t+1 in flight)
    __builtin_amdgcn_s_barrier();           // all 4 chunks of step t in LDS
    __builtin_amdgcn_sched_barrier(0);

    const int buf = t & 1;
    // ---- two fence-free 64-row sub-tiles per step ----
#pragma unroll
    for (int s = 0; s < 2; ++s) {
      const char* kld = (const char*)&kv[buf][s][0]     + lane * 16;
      const char* vld = (const char*)&kv[buf][2 + s][0] + lane * 16;
      f32x16 s0 = {}, s1 = {};
#pragma unroll
      for (int c = 0; c < 4; ++c) {
        s0 = MFMA32(*(const bf16x8*)(kld + c * 1024),        qf[c], s0);
        s1 = MFMA32(*(const bf16x8*)(kld + 4096 + c * 1024), qf[c], s1);
      }
      softmax_pa(s0, s1);
#pragma unroll
      for (int c = 0; c < 4; ++c) {
        acc0 = MFMA32(pa[c], *(const bf16x8*)(vld + c * 1024),        acc0);
        acc1 = MFMA32(pa[c], *(const bf16x8*)(vld + 4096 + c * 1024), acc1);
      }
    }

    __builtin_amdgcn_sched_barrier(0);
    __builtin_amdgcn_s_barrier();           // all reads of buf done block-wide
    stage(buf, (t + 2) & 15);               // DMA step t+2 (wrap = harmless dummy)
  }
  wait0();   // drain the dummy wrap DMAs

  // ---- merge cross-half l, normalize, store this wave's 32 rows ----
  {
    int a = __float_as_int(l), b = a;
    plswap(a, b);
    l = __int_as_float(a) + __int_as_float(b);
  }
  const float linv = 1.0f / l;
#pragma unroll
  for (int r = 0; r < 16; ++r) {
    int qr = (r & 3) + 8 * (r >> 2) + 4 * hi;
    float li = __shfl(linv, qr);   // row qr's sum lives in lane qr (both halves merged)
    float* orow = Og + base + (size_t)(qb * 128 + wid * 32 + qr) * ROWS;
    orow[lq]      = acc0[r] * li;
    orow[32 + lq] = acc1[r] * li;
  }
}

extern "C" void kernel_launch(void* const* d_in, const int* in_sizes, int n_in,
                              void* d_out, int out_size, void* d_ws, size_t ws_size,
                              hipStream_t stream) {
  const float* Q = (const float*)d_in[0];
  const float* K = (const float*)d_in[1];
  const float* V = (const float*)d_in[2];
  float* O = (float*)d_out;
  preconv<<<dim3(1024), dim3(256), 0, stream>>>(K, V);
  attn_fwd<<<dim3(512), dim3(256), 0, stream>>>(Q, O);
}